// Round 12
// baseline (118.058 us; speedup 1.0000x reference)
//
#include <hip/hip_runtime.h>
#include <stdint.h>

// Shapes fixed by setup_inputs(): x [8192,512] f32, patterns [1024,512] f32,
// edges [7] f32. Outputs: [8192] argmax idx (as f32) ++ [8192] score (cnt/512).
//
// R12: MEASUREMENT ROUND. R9 (best, 85.7us) verbatim, but match_kernel is
// launched 3x (idempotent: pure function of prep outputs, plain stores of the
// same values). dur_us = base + 2*(match + launch_overhead) -- finally pins
// down where the ~40us controllable budget actually lives, since our kernels
// never appear in the rocprof top-5 (all slots taken by the harness's ~43us
// 268MB d_ws poison fills).
#define NROW 8192
#define NPAT 1024

typedef unsigned long long u64;
typedef unsigned int u32;
typedef unsigned char u8;
typedef __attribute__((ext_vector_type(4))) int i32x4;
typedef __attribute__((ext_vector_type(8))) int i32x8;
typedef __attribute__((ext_vector_type(16))) float f32x16;

__device__ __forceinline__ u32 bin7(float v, float e0, float e1, float e2,
                                    float e3, float e4, float e5, float e6) {
  return (u32)((v > e0) + (v > e1) + (v > e2) + (v > e3) + (v > e4) +
               (v > e5) + (v > e6));
}

// Quantize 16 consecutive dims -> 16 code bytes, PRE-SHIFTED (bin*4).
__device__ __forceinline__ int4 quant16n(const float4* s4, float e0, float e1,
                                         float e2, float e3, float e4,
                                         float e5, float e6) {
  int4 out;
  int* od = &out.x;
#pragma unroll
  for (int q = 0; q < 4; ++q) {
    float4 a = s4[q];
    od[q] = (int)((bin7(a.x, e0, e1, e2, e3, e4, e5, e6) << 2) |
                  ((bin7(a.y, e0, e1, e2, e3, e4, e5, e6) << 2) << 8) |
                  ((bin7(a.z, e0, e1, e2, e3, e4, e5, e6) << 2) << 16) |
                  ((bin7(a.w, e0, e1, e2, e3, e4, e5, e6) << 2) << 24));
  }
  return out;
}

// ---------------------------------------------------------------------------
// Prep: codes layout [c16 0..31][h 0..1][row][8B]: 8 dims per 8-byte cell,
// so a lane's k-half (h = lane>>5) for one 16-dim iteration is ONE dwordx2.
// ---------------------------------------------------------------------------
__global__ __launch_bounds__(256) void prep_kernel(
    const float* __restrict__ x, const float* __restrict__ patterns,
    const float* __restrict__ edges, u8* __restrict__ xcode2,
    u8* __restrict__ qpc2) {
  const float e0 = edges[0], e1 = edges[1], e2 = edges[2], e3 = edges[3],
              e4 = edges[4], e5 = edges[5], e6 = edges[6];
  const int bid = blockIdx.x, tid = threadIdx.x;

  if (bid < 1024) {
    const int i = bid * 256 + tid;  // 0..262143
    const int row = i & 8191;
    const int c16 = i >> 13;
    const float4* s4 =
        reinterpret_cast<const float4*>(x + ((size_t)row << 9) + (c16 << 4));
    int4 cod = quant16n(s4, e0, e1, e2, e3, e4, e5, e6);
    const u64 lo = (u64)(u32)cod.x | ((u64)(u32)cod.y << 32);  // dims 0..7
    const u64 hi = (u64)(u32)cod.z | ((u64)(u32)cod.w << 32);  // dims 8..15
    *reinterpret_cast<u64*>(
        xcode2 + ((((size_t)c16 * 2 + 0) * 8192 + row) << 3)) = lo;
    *reinterpret_cast<u64*>(
        xcode2 + ((((size_t)c16 * 2 + 1) * 8192 + row) << 3)) = hi;
  } else {
    const int j = (bid - 1024) * 256 + tid;  // 0..32767
    const int pat = j >> 5;
    const int c16 = j & 31;
    const float4* s4 = reinterpret_cast<const float4*>(
        patterns + ((size_t)pat << 9) + (c16 << 4));
    int4 cod = quant16n(s4, e0, e1, e2, e3, e4, e5, e6);
    const u64 lo = (u64)(u32)cod.x | ((u64)(u32)cod.y << 32);
    const u64 hi = (u64)(u32)cod.z | ((u64)(u32)cod.w << 32);
    *reinterpret_cast<u64*>(
        qpc2 + ((((size_t)c16 * 2 + 0) * 1024 + pat) << 3)) = lo;
    *reinterpret_cast<u64*>(
        qpc2 + ((((size_t)c16 * 2 + 1) * 1024 + pat) << 3)) = hi;
  }
}

// Expand 4 dims (pre-shifted codes bin*4 in the 4 bytes of w) into 4 dwords
// of fp4 one-hot nibbles (1.0 = 0x2 at nibble bin). IDENTICAL for A and B.
__device__ __forceinline__ i32x4 expand4(u32 w) {
  i32x4 f;
  f[0] = (int)(2u << (w & 0xFFu));
  f[1] = (int)(2u << ((w >> 8) & 0xFFu));
  f[2] = (int)(2u << ((w >> 16) & 0xFFu));
  f[3] = (int)(2u << (w >> 24));
  return f;
}

__device__ __forceinline__ i32x8 make8(i32x4 v) {
  i32x8 r;
  r[0] = v[0]; r[1] = v[1]; r[2] = v[2]; r[3] = v[3];
  r[4] = 0; r[5] = 0; r[6] = 0; r[7] = 0;  // fp4 uses operand regs 0-3
  return r;
}

#define MFMA_FP4(A, B, C)                                                \
  __builtin_amdgcn_mfma_scale_f32_32x32x64_f8f6f4(                       \
      (A), (B), (C), 4, 4, 0, 0x7F7F7F7F, 0, 0x7F7F7F7F)

// ---------------------------------------------------------------------------
// Match+argmax (R9 verbatim). Grid 256 blocks x 512 thr (8 waves, 1 block/CU).
// Block b: rows b*32..+31, ALL 1024 patterns. Wave w: patterns w*128 + q*32,
// q=0..3 (4 fp32 accs). B fragment shared by 4 accs. Software prefetch.
// Epilogue: packed keys -> LDS+shuffle argmax, wave 0 writes out[] directly.
// IDEMPOTENT: reads only prep outputs, writes the same values every launch.
// ---------------------------------------------------------------------------
__global__ __launch_bounds__(512, 2) void match_kernel(
    const u8* __restrict__ xcode2,  // [32][2][8192][8]
    const u8* __restrict__ qpc2,    // [32][2][1024][8]
    float* __restrict__ out) {
  __shared__ u32 lds_best[8][64];  // 2 KB

  const int tid = threadIdx.x;
  const int lane = tid & 63;
  const int h = lane >> 5;
  const int wid = tid >> 6;  // 0..7
  const int row = blockIdx.x * 32 + (lane & 31);
  const int m0 = wid * 128 + (lane & 31);

  const u8* pR = xcode2 + (((size_t)h * 8192 + row) << 3);
  const u8* pP = qpc2 + (((size_t)h * 1024 + m0) << 3);

  f32x16 acc0 = {0}, acc1 = {0}, acc2 = {0}, acc3 = {0};

  u64 cR = *reinterpret_cast<const u64*>(pR);
  u64 cP0 = *reinterpret_cast<const u64*>(pP);
  u64 cP1 = *reinterpret_cast<const u64*>(pP + 256);
  u64 cP2 = *reinterpret_cast<const u64*>(pP + 512);
  u64 cP3 = *reinterpret_cast<const u64*>(pP + 768);

  for (int c = 0; c < 32; ++c) {
    u64 nR, nP0, nP1, nP2, nP3;
    if (c < 31) {
      const size_t ro = (size_t)(c + 1) << 17;  // 2*8192*8 B per iteration
      const size_t po = (size_t)(c + 1) << 14;  // 2*1024*8 B per iteration
      nR = *reinterpret_cast<const u64*>(pR + ro);
      nP0 = *reinterpret_cast<const u64*>(pP + po);
      nP1 = *reinterpret_cast<const u64*>(pP + po + 256);
      nP2 = *reinterpret_cast<const u64*>(pP + po + 512);
      nP3 = *reinterpret_cast<const u64*>(pP + po + 768);
    }
#pragma unroll
    for (int j = 0; j < 2; ++j) {
      const i32x8 b8 = make8(expand4((u32)(cR >> (32 * j))));
      const i32x8 a0 = make8(expand4((u32)(cP0 >> (32 * j))));
      const i32x8 a1 = make8(expand4((u32)(cP1 >> (32 * j))));
      const i32x8 a2 = make8(expand4((u32)(cP2 >> (32 * j))));
      const i32x8 a3 = make8(expand4((u32)(cP3 >> (32 * j))));
      acc0 = MFMA_FP4(a0, b8, acc0);
      acc1 = MFMA_FP4(a1, b8, acc1);
      acc2 = MFMA_FP4(a2, b8, acc2);
      acc3 = MFMA_FP4(a3, b8, acc3);
    }
    if (c < 31) {
      cR = nR;
      cP0 = nP0;
      cP1 = nP1;
      cP2 = nP2;
      cP3 = nP3;
    }
  }

  // Fold accs -> one packed key. C/D map (shape-determined, HW-verified):
  // col = lane&31 (this lane's row), pl = (r&3) + 8*(r>>2) + 4*h.
  const int hq = h << 2;
  const int wbase = wid * 128;
  u32 best = 0;
#pragma unroll
  for (int r = 0; r < 16; ++r) {
    const int pl = (r & 3) + 8 * (r >> 2) + hq;
    const u32 k0 = (((u32)acc0[r]) << 10) | (1023u - (u32)(wbase + pl));
    const u32 k1 = (((u32)acc1[r]) << 10) | (1023u - (u32)(wbase + 32 + pl));
    const u32 k2 = (((u32)acc2[r]) << 10) | (1023u - (u32)(wbase + 64 + pl));
    const u32 k3 = (((u32)acc3[r]) << 10) | (1023u - (u32)(wbase + 96 + pl));
    best = k0 > best ? k0 : best;
    best = k1 > best ? k1 : best;
    best = k2 > best ? k2 : best;
    best = k3 > best ? k3 : best;
  }
  lds_best[wid][lane] = best;
  __syncthreads();

  if (wid == 0) {
    u32 t = lds_best[0][lane];
#pragma unroll
    for (int w = 1; w < 8; ++w) {
      const u32 v = lds_best[w][lane];
      t = v > t ? v : t;
    }
    const u32 o = __shfl_down(t, 32);
    if (lane < 32) {
      const u32 f = o > t ? o : t;
      out[row] = (float)(1023u - (f & 1023u));
      out[NROW + row] = (float)(f >> 10) * (1.0f / 512.0f);
    }
  }
}

extern "C" void kernel_launch(void* const* d_in, const int* in_sizes, int n_in,
                              void* d_out, int out_size, void* d_ws,
                              size_t ws_size, hipStream_t stream) {
  const float* x = (const float*)d_in[0];         // [8192, 512]
  const float* patterns = (const float*)d_in[1];  // [1024, 512]
  const float* edges = (const float*)d_in[2];     // [7]
  float* out = (float*)d_out;                     // 16384 floats

  // Workspace: xcode2 4MB ++ qpc2 512KB.
  u8* xcode2 = (u8*)d_ws;                     // [32][2][8192][8]
  u8* qpc2 = xcode2 + (size_t)64 * NROW * 8;  // [32][2][1024][8]

  prep_kernel<<<1152, 256, 0, stream>>>(x, patterns, edges, xcode2, qpc2);
  // PROBE: match launched 3x (idempotent). dur_us - R9_base = 2*(match+L).
  match_kernel<<<256, 512, 0, stream>>>(xcode2, qpc2, out);
  match_kernel<<<256, 512, 0, stream>>>(xcode2, qpc2, out);
  match_kernel<<<256, 512, 0, stream>>>(xcode2, qpc2, out);
}

// Round 13
// 88.434 us; speedup vs baseline: 1.3350x; 1.3350x over previous
//
#include <hip/hip_runtime.h>
#include <stdint.h>

// Shapes fixed by setup_inputs(): x [8192,512] f32, patterns [1024,512] f32,
// edges [7] f32. Outputs: [8192] argmax idx (as f32) ++ [8192] score (cnt/512).
//
// R13: R9 structure (best measured; match+L = 16.2us via R12 probe) with the
// hot loop de-stalled: depth-2 software prefetch issued at chunk top
// (branchless; over-read of chunks 32/33 lands in allocated-unused ws) and
// operand-tuple zero-halves hoisted out of the loop (no per-chunk make8
// re-zeroing). Numerics identical to R9 (proven exact).
#define NROW 8192
#define NPAT 1024

typedef unsigned long long u64;
typedef unsigned int u32;
typedef unsigned char u8;
typedef __attribute__((ext_vector_type(4))) int i32x4;
typedef __attribute__((ext_vector_type(8))) int i32x8;
typedef __attribute__((ext_vector_type(16))) float f32x16;

__device__ __forceinline__ u32 bin7(float v, float e0, float e1, float e2,
                                    float e3, float e4, float e5, float e6) {
  return (u32)((v > e0) + (v > e1) + (v > e2) + (v > e3) + (v > e4) +
               (v > e5) + (v > e6));
}

// Quantize 16 consecutive dims -> 16 code bytes, PRE-SHIFTED (bin*4).
__device__ __forceinline__ int4 quant16n(const float4* s4, float e0, float e1,
                                         float e2, float e3, float e4,
                                         float e5, float e6) {
  int4 out;
  int* od = &out.x;
#pragma unroll
  for (int q = 0; q < 4; ++q) {
    float4 a = s4[q];
    od[q] = (int)((bin7(a.x, e0, e1, e2, e3, e4, e5, e6) << 2) |
                  ((bin7(a.y, e0, e1, e2, e3, e4, e5, e6) << 2) << 8) |
                  ((bin7(a.z, e0, e1, e2, e3, e4, e5, e6) << 2) << 16) |
                  ((bin7(a.w, e0, e1, e2, e3, e4, e5, e6) << 2) << 24));
  }
  return out;
}

// ---------------------------------------------------------------------------
// Prep: codes layout [c16 0..31][h 0..1][row][8B]: 8 dims per 8-byte cell,
// so a lane's k-half (h = lane>>5) for one 16-dim iteration is ONE dwordx2.
// ---------------------------------------------------------------------------
__global__ __launch_bounds__(256) void prep_kernel(
    const float* __restrict__ x, const float* __restrict__ patterns,
    const float* __restrict__ edges, u8* __restrict__ xcode2,
    u8* __restrict__ qpc2) {
  const float e0 = edges[0], e1 = edges[1], e2 = edges[2], e3 = edges[3],
              e4 = edges[4], e5 = edges[5], e6 = edges[6];
  const int bid = blockIdx.x, tid = threadIdx.x;

  if (bid < 1024) {
    const int i = bid * 256 + tid;  // 0..262143
    const int row = i & 8191;
    const int c16 = i >> 13;
    const float4* s4 =
        reinterpret_cast<const float4*>(x + ((size_t)row << 9) + (c16 << 4));
    int4 cod = quant16n(s4, e0, e1, e2, e3, e4, e5, e6);
    const u64 lo = (u64)(u32)cod.x | ((u64)(u32)cod.y << 32);  // dims 0..7
    const u64 hi = (u64)(u32)cod.z | ((u64)(u32)cod.w << 32);  // dims 8..15
    *reinterpret_cast<u64*>(
        xcode2 + ((((size_t)c16 * 2 + 0) * 8192 + row) << 3)) = lo;
    *reinterpret_cast<u64*>(
        xcode2 + ((((size_t)c16 * 2 + 1) * 8192 + row) << 3)) = hi;
  } else {
    const int j = (bid - 1024) * 256 + tid;  // 0..32767
    const int pat = j >> 5;
    const int c16 = j & 31;
    const float4* s4 = reinterpret_cast<const float4*>(
        patterns + ((size_t)pat << 9) + (c16 << 4));
    int4 cod = quant16n(s4, e0, e1, e2, e3, e4, e5, e6);
    const u64 lo = (u64)(u32)cod.x | ((u64)(u32)cod.y << 32);
    const u64 hi = (u64)(u32)cod.z | ((u64)(u32)cod.w << 32);
    *reinterpret_cast<u64*>(
        qpc2 + ((((size_t)c16 * 2 + 0) * 1024 + pat) << 3)) = lo;
    *reinterpret_cast<u64*>(
        qpc2 + ((((size_t)c16 * 2 + 1) * 1024 + pat) << 3)) = hi;
  }
}

#define MFMA_FP4(A, B, C)                                                \
  __builtin_amdgcn_mfma_scale_f32_32x32x64_f8f6f4(                       \
      (A), (B), (C), 4, 4, 0, 0x7F7F7F7F, 0, 0x7F7F7F7F)

// ---------------------------------------------------------------------------
// Match+argmax. Grid 256 blocks x 512 thr (8 waves, 1 block/CU). Block b:
// rows b*32..+31, ALL 1024 patterns. Wave w: patterns w*128 + q*32, q=0..3.
// Per chunk: 5 u64 code loads (depth-2 prefetched), in-register fp4 one-hot
// expansion into PERSISTENT 8-reg tuples (high halves zeroed once), 8 MFMAs.
// Epilogue: packed keys -> LDS+shuffle argmax, wave 0 writes out[] directly.
// ---------------------------------------------------------------------------
__global__ __launch_bounds__(512, 2) void match_kernel(
    const u8* __restrict__ xcode2,  // [32][2][8192][8]
    const u8* __restrict__ qpc2,    // [32][2][1024][8]
    float* __restrict__ out) {
  __shared__ u32 lds_best[8][64];  // 2 KB

  const int tid = threadIdx.x;
  const int lane = tid & 63;
  const int h = lane >> 5;
  const int wid = tid >> 6;  // 0..7
  const int row = blockIdx.x * 32 + (lane & 31);
  const int m0 = wid * 128 + (lane & 31);

  const u8* pR = xcode2 + (((size_t)h * 8192 + row) << 3);
  const u8* pP = qpc2 + (((size_t)h * 1024 + m0) << 3);

  f32x16 acc0 = {0}, acc1 = {0}, acc2 = {0}, acc3 = {0};

  // Persistent operand tuples: high halves zeroed ONCE (fp4 uses regs 0-3).
  i32x8 b8 = {0}, a0 = {0}, a1 = {0}, a2 = {0}, a3 = {0};

  // Depth-2 pipeline registers. Over-reads for c=32,33 land in allocated-
  // but-unused workspace (ws is 256MB; we use <5MB) -- values never consumed.
  u64 cR0, cP00, cP10, cP20, cP30;   // chunk c
  u64 cR1, cP01, cP11, cP21, cP31;   // chunk c+1
  cR0 = *reinterpret_cast<const u64*>(pR);
  cP00 = *reinterpret_cast<const u64*>(pP);
  cP10 = *reinterpret_cast<const u64*>(pP + 256);
  cP20 = *reinterpret_cast<const u64*>(pP + 512);
  cP30 = *reinterpret_cast<const u64*>(pP + 768);
  cR1 = *reinterpret_cast<const u64*>(pR + ((size_t)1 << 17));
  cP01 = *reinterpret_cast<const u64*>(pP + ((size_t)1 << 14));
  cP11 = *reinterpret_cast<const u64*>(pP + ((size_t)1 << 14) + 256);
  cP21 = *reinterpret_cast<const u64*>(pP + ((size_t)1 << 14) + 512);
  cP31 = *reinterpret_cast<const u64*>(pP + ((size_t)1 << 14) + 768);

  for (int c = 0; c < 32; ++c) {
    // Issue chunk c+2 loads FIRST -- two full chunks of latency cover.
    const size_t ro = (size_t)(c + 2) << 17;  // 2*8192*8 B per chunk
    const size_t po = (size_t)(c + 2) << 14;  // 2*1024*8 B per chunk
    const u64 fR = *reinterpret_cast<const u64*>(pR + ro);
    const u64 fP0 = *reinterpret_cast<const u64*>(pP + po);
    const u64 fP1 = *reinterpret_cast<const u64*>(pP + po + 256);
    const u64 fP2 = *reinterpret_cast<const u64*>(pP + po + 512);
    const u64 fP3 = *reinterpret_cast<const u64*>(pP + po + 768);

#pragma unroll
    for (int j = 0; j < 2; ++j) {
      const u32 wR = (u32)(cR0 >> (32 * j));
      const u32 wP0 = (u32)(cP00 >> (32 * j));
      const u32 wP1 = (u32)(cP10 >> (32 * j));
      const u32 wP2 = (u32)(cP20 >> (32 * j));
      const u32 wP3 = (u32)(cP30 >> (32 * j));
      // fp4 one-hot nibble: 1.0 = 0x2 at nibble bin (codes pre-shifted *4).
#pragma unroll
      for (int t = 0; t < 4; ++t) {
        b8[t] = (int)(2u << ((wR >> (8 * t)) & 0xFFu));
        a0[t] = (int)(2u << ((wP0 >> (8 * t)) & 0xFFu));
        a1[t] = (int)(2u << ((wP1 >> (8 * t)) & 0xFFu));
        a2[t] = (int)(2u << ((wP2 >> (8 * t)) & 0xFFu));
        a3[t] = (int)(2u << ((wP3 >> (8 * t)) & 0xFFu));
      }
      acc0 = MFMA_FP4(a0, b8, acc0);
      acc1 = MFMA_FP4(a1, b8, acc1);
      acc2 = MFMA_FP4(a2, b8, acc2);
      acc3 = MFMA_FP4(a3, b8, acc3);
    }

    // Rotate pipeline.
    cR0 = cR1;  cP00 = cP01;  cP10 = cP11;  cP20 = cP21;  cP30 = cP31;
    cR1 = fR;   cP01 = fP0;   cP11 = fP1;   cP21 = fP2;   cP31 = fP3;
  }

  // Fold accs -> one packed key. C/D map (shape-determined, HW-verified):
  // col = lane&31 (this lane's row), pl = (r&3) + 8*(r>>2) + 4*h.
  const int hq = h << 2;
  const int wbase = wid * 128;
  u32 best = 0;
#pragma unroll
  for (int r = 0; r < 16; ++r) {
    const int pl = (r & 3) + 8 * (r >> 2) + hq;
    const u32 k0 = (((u32)acc0[r]) << 10) | (1023u - (u32)(wbase + pl));
    const u32 k1 = (((u32)acc1[r]) << 10) | (1023u - (u32)(wbase + 32 + pl));
    const u32 k2 = (((u32)acc2[r]) << 10) | (1023u - (u32)(wbase + 64 + pl));
    const u32 k3 = (((u32)acc3[r]) << 10) | (1023u - (u32)(wbase + 96 + pl));
    best = k0 > best ? k0 : best;
    best = k1 > best ? k1 : best;
    best = k2 > best ? k2 : best;
    best = k3 > best ? k3 : best;
  }
  lds_best[wid][lane] = best;
  __syncthreads();

  if (wid == 0) {
    u32 t = lds_best[0][lane];
#pragma unroll
    for (int w = 1; w < 8; ++w) {
      const u32 v = lds_best[w][lane];
      t = v > t ? v : t;
    }
    const u32 o = __shfl_down(t, 32);
    if (lane < 32) {
      const u32 f = o > t ? o : t;
      out[row] = (float)(1023u - (f & 1023u));
      out[NROW + row] = (float)(f >> 10) * (1.0f / 512.0f);
    }
  }
}

extern "C" void kernel_launch(void* const* d_in, const int* in_sizes, int n_in,
                              void* d_out, int out_size, void* d_ws,
                              size_t ws_size, hipStream_t stream) {
  const float* x = (const float*)d_in[0];         // [8192, 512]
  const float* patterns = (const float*)d_in[1];  // [1024, 512]
  const float* edges = (const float*)d_in[2];     // [7]
  float* out = (float*)d_out;                     // 16384 floats

  // Workspace: xcode2 4MB ++ qpc2 512KB (+64KB over-read slack, ws is 256MB).
  u8* xcode2 = (u8*)d_ws;                     // [32][2][8192][8]
  u8* qpc2 = xcode2 + (size_t)64 * NROW * 8;  // [32][2][1024][8]

  prep_kernel<<<1152, 256, 0, stream>>>(x, patterns, edges, xcode2, qpc2);
  match_kernel<<<256, 512, 0, stream>>>(xcode2, qpc2, out);
}

// Round 14
// 85.658 us; speedup vs baseline: 1.3783x; 1.0324x over previous
//
#include <hip/hip_runtime.h>
#include <stdint.h>

// Shapes fixed by setup_inputs(): x [8192,512] f32, patterns [1024,512] f32,
// edges [7] f32. Outputs: [8192] argmax idx (as f32) ++ [8192] score (cnt/512).
//
// R14: R9 verbatim (best, 85.7us; match ~13us vs 7.6us fp4-MFMA floor) plus
// ONE change: anti-phase wave stagger. The two co-resident waves per SIMD are
// phase-locked (identical streams, same start) -> expand-VALU and MFMA phases
// serialize chip-wide (R12 probe: ~1000 cyc/chunk/SIMD = exact serial sum).
// Half the waves (split within each SIMD-resident pair under either wid%4 or
// wid>>1 mapping) sleep ~512 cyc at entry = half the chunk period, so one
// wave's MFMA phase overlays the other's VALU phase (m114 co-issue).
#define NROW 8192
#define NPAT 1024

typedef unsigned long long u64;
typedef unsigned int u32;
typedef unsigned char u8;
typedef __attribute__((ext_vector_type(4))) int i32x4;
typedef __attribute__((ext_vector_type(8))) int i32x8;
typedef __attribute__((ext_vector_type(16))) float f32x16;

__device__ __forceinline__ u32 bin7(float v, float e0, float e1, float e2,
                                    float e3, float e4, float e5, float e6) {
  return (u32)((v > e0) + (v > e1) + (v > e2) + (v > e3) + (v > e4) +
               (v > e5) + (v > e6));
}

// Quantize 16 consecutive dims -> 16 code bytes, PRE-SHIFTED (bin*4).
__device__ __forceinline__ int4 quant16n(const float4* s4, float e0, float e1,
                                         float e2, float e3, float e4,
                                         float e5, float e6) {
  int4 out;
  int* od = &out.x;
#pragma unroll
  for (int q = 0; q < 4; ++q) {
    float4 a = s4[q];
    od[q] = (int)((bin7(a.x, e0, e1, e2, e3, e4, e5, e6) << 2) |
                  ((bin7(a.y, e0, e1, e2, e3, e4, e5, e6) << 2) << 8) |
                  ((bin7(a.z, e0, e1, e2, e3, e4, e5, e6) << 2) << 16) |
                  ((bin7(a.w, e0, e1, e2, e3, e4, e5, e6) << 2) << 24));
  }
  return out;
}

// ---------------------------------------------------------------------------
// Prep: codes layout [c16 0..31][h 0..1][row][8B]: 8 dims per 8-byte cell,
// so a lane's k-half (h = lane>>5) for one 16-dim iteration is ONE dwordx2.
// ---------------------------------------------------------------------------
__global__ __launch_bounds__(256) void prep_kernel(
    const float* __restrict__ x, const float* __restrict__ patterns,
    const float* __restrict__ edges, u8* __restrict__ xcode2,
    u8* __restrict__ qpc2) {
  const float e0 = edges[0], e1 = edges[1], e2 = edges[2], e3 = edges[3],
              e4 = edges[4], e5 = edges[5], e6 = edges[6];
  const int bid = blockIdx.x, tid = threadIdx.x;

  if (bid < 1024) {
    const int i = bid * 256 + tid;  // 0..262143
    const int row = i & 8191;
    const int c16 = i >> 13;
    const float4* s4 =
        reinterpret_cast<const float4*>(x + ((size_t)row << 9) + (c16 << 4));
    int4 cod = quant16n(s4, e0, e1, e2, e3, e4, e5, e6);
    const u64 lo = (u64)(u32)cod.x | ((u64)(u32)cod.y << 32);  // dims 0..7
    const u64 hi = (u64)(u32)cod.z | ((u64)(u32)cod.w << 32);  // dims 8..15
    *reinterpret_cast<u64*>(
        xcode2 + ((((size_t)c16 * 2 + 0) * 8192 + row) << 3)) = lo;
    *reinterpret_cast<u64*>(
        xcode2 + ((((size_t)c16 * 2 + 1) * 8192 + row) << 3)) = hi;
  } else {
    const int j = (bid - 1024) * 256 + tid;  // 0..32767
    const int pat = j >> 5;
    const int c16 = j & 31;
    const float4* s4 = reinterpret_cast<const float4*>(
        patterns + ((size_t)pat << 9) + (c16 << 4));
    int4 cod = quant16n(s4, e0, e1, e2, e3, e4, e5, e6);
    const u64 lo = (u64)(u32)cod.x | ((u64)(u32)cod.y << 32);
    const u64 hi = (u64)(u32)cod.z | ((u64)(u32)cod.w << 32);
    *reinterpret_cast<u64*>(
        qpc2 + ((((size_t)c16 * 2 + 0) * 1024 + pat) << 3)) = lo;
    *reinterpret_cast<u64*>(
        qpc2 + ((((size_t)c16 * 2 + 1) * 1024 + pat) << 3)) = hi;
  }
}

// Expand 4 dims (pre-shifted codes bin*4 in the 4 bytes of w) into 4 dwords
// of fp4 one-hot nibbles (1.0 = 0x2 at nibble bin). IDENTICAL for A and B.
__device__ __forceinline__ i32x4 expand4(u32 w) {
  i32x4 f;
  f[0] = (int)(2u << (w & 0xFFu));
  f[1] = (int)(2u << ((w >> 8) & 0xFFu));
  f[2] = (int)(2u << ((w >> 16) & 0xFFu));
  f[3] = (int)(2u << (w >> 24));
  return f;
}

__device__ __forceinline__ i32x8 make8(i32x4 v) {
  i32x8 r;
  r[0] = v[0]; r[1] = v[1]; r[2] = v[2]; r[3] = v[3];
  r[4] = 0; r[5] = 0; r[6] = 0; r[7] = 0;  // fp4 uses operand regs 0-3
  return r;
}

#define MFMA_FP4(A, B, C)                                                \
  __builtin_amdgcn_mfma_scale_f32_32x32x64_f8f6f4(                       \
      (A), (B), (C), 4, 4, 0, 0x7F7F7F7F, 0, 0x7F7F7F7F)

// ---------------------------------------------------------------------------
// Match+argmax (R9 verbatim + stagger). Grid 256 x 512 thr (8 waves,
// 1 block/CU, 2 waves/SIMD). Block b: rows b*32..+31, ALL 1024 patterns.
// Wave w: patterns w*128 + q*32, q=0..3 (4 fp32 accs). B fragment shared by
// 4 accs. Software prefetch depth 1. Epilogue: packed keys -> LDS+shuffle
// argmax, wave 0 writes out[] directly.
// ---------------------------------------------------------------------------
__global__ __launch_bounds__(512, 2) void match_kernel(
    const u8* __restrict__ xcode2,  // [32][2][8192][8]
    const u8* __restrict__ qpc2,    // [32][2][1024][8]
    float* __restrict__ out) {
  __shared__ u32 lds_best[8][64];  // 2 KB

  const int tid = threadIdx.x;
  const int lane = tid & 63;
  const int h = lane >> 5;
  const int wid = tid >> 6;  // 0..7
  const int row = blockIdx.x * 32 + (lane & 31);
  const int m0 = wid * 128 + (lane & 31);

  // ANTI-PHASE STAGGER: de-phase the two co-resident waves per SIMD.
  // Key differs within each pair under both wid%4 and wid>>1 mappings.
  if (((wid >> 2) ^ wid) & 1) __builtin_amdgcn_s_sleep(8);  // ~512 cyc

  const u8* pR = xcode2 + (((size_t)h * 8192 + row) << 3);
  const u8* pP = qpc2 + (((size_t)h * 1024 + m0) << 3);

  f32x16 acc0 = {0}, acc1 = {0}, acc2 = {0}, acc3 = {0};

  u64 cR = *reinterpret_cast<const u64*>(pR);
  u64 cP0 = *reinterpret_cast<const u64*>(pP);
  u64 cP1 = *reinterpret_cast<const u64*>(pP + 256);
  u64 cP2 = *reinterpret_cast<const u64*>(pP + 512);
  u64 cP3 = *reinterpret_cast<const u64*>(pP + 768);

  for (int c = 0; c < 32; ++c) {
    u64 nR, nP0, nP1, nP2, nP3;
    if (c < 31) {
      const size_t ro = (size_t)(c + 1) << 17;  // 2*8192*8 B per iteration
      const size_t po = (size_t)(c + 1) << 14;  // 2*1024*8 B per iteration
      nR = *reinterpret_cast<const u64*>(pR + ro);
      nP0 = *reinterpret_cast<const u64*>(pP + po);
      nP1 = *reinterpret_cast<const u64*>(pP + po + 256);
      nP2 = *reinterpret_cast<const u64*>(pP + po + 512);
      nP3 = *reinterpret_cast<const u64*>(pP + po + 768);
    }
#pragma unroll
    for (int j = 0; j < 2; ++j) {
      const i32x8 b8 = make8(expand4((u32)(cR >> (32 * j))));
      const i32x8 a0 = make8(expand4((u32)(cP0 >> (32 * j))));
      const i32x8 a1 = make8(expand4((u32)(cP1 >> (32 * j))));
      const i32x8 a2 = make8(expand4((u32)(cP2 >> (32 * j))));
      const i32x8 a3 = make8(expand4((u32)(cP3 >> (32 * j))));
      acc0 = MFMA_FP4(a0, b8, acc0);
      acc1 = MFMA_FP4(a1, b8, acc1);
      acc2 = MFMA_FP4(a2, b8, acc2);
      acc3 = MFMA_FP4(a3, b8, acc3);
    }
    if (c < 31) {
      cR = nR;
      cP0 = nP0;
      cP1 = nP1;
      cP2 = nP2;
      cP3 = nP3;
    }
  }

  // Fold accs -> one packed key. C/D map (shape-determined, HW-verified):
  // col = lane&31 (this lane's row), pl = (r&3) + 8*(r>>2) + 4*h.
  const int hq = h << 2;
  const int wbase = wid * 128;
  u32 best = 0;
#pragma unroll
  for (int r = 0; r < 16; ++r) {
    const int pl = (r & 3) + 8 * (r >> 2) + hq;
    const u32 k0 = (((u32)acc0[r]) << 10) | (1023u - (u32)(wbase + pl));
    const u32 k1 = (((u32)acc1[r]) << 10) | (1023u - (u32)(wbase + 32 + pl));
    const u32 k2 = (((u32)acc2[r]) << 10) | (1023u - (u32)(wbase + 64 + pl));
    const u32 k3 = (((u32)acc3[r]) << 10) | (1023u - (u32)(wbase + 96 + pl));
    best = k0 > best ? k0 : best;
    best = k1 > best ? k1 : best;
    best = k2 > best ? k2 : best;
    best = k3 > best ? k3 : best;
  }
  lds_best[wid][lane] = best;
  __syncthreads();

  if (wid == 0) {
    u32 t = lds_best[0][lane];
#pragma unroll
    for (int w = 1; w < 8; ++w) {
      const u32 v = lds_best[w][lane];
      t = v > t ? v : t;
    }
    const u32 o = __shfl_down(t, 32);
    if (lane < 32) {
      const u32 f = o > t ? o : t;
      out[row] = (float)(1023u - (f & 1023u));
      out[NROW + row] = (float)(f >> 10) * (1.0f / 512.0f);
    }
  }
}

extern "C" void kernel_launch(void* const* d_in, const int* in_sizes, int n_in,
                              void* d_out, int out_size, void* d_ws,
                              size_t ws_size, hipStream_t stream) {
  const float* x = (const float*)d_in[0];         // [8192, 512]
  const float* patterns = (const float*)d_in[1];  // [1024, 512]
  const float* edges = (const float*)d_in[2];     // [7]
  float* out = (float*)d_out;                     // 16384 floats

  // Workspace: xcode2 4MB ++ qpc2 512KB.
  u8* xcode2 = (u8*)d_ws;                     // [32][2][8192][8]
  u8* qpc2 = xcode2 + (size_t)64 * NROW * 8;  // [32][2][1024][8]

  prep_kernel<<<1152, 256, 0, stream>>>(x, patterns, edges, xcode2, qpc2);
  match_kernel<<<256, 512, 0, stream>>>(xcode2, qpc2, out);
}

// Round 15
// 85.422 us; speedup vs baseline: 1.3821x; 1.0028x over previous
//
#include <hip/hip_runtime.h>
#include <stdint.h>

// Shapes fixed by setup_inputs(): x [8192,512] f32, patterns [1024,512] f32,
// edges [7] f32. Outputs: [8192] argmax idx (as f32) ++ [8192] score (cnt/512).
//
// R15: R9 verbatim except accumulator SPLIT: j=0 MFMAs -> acc*a, j=1 -> acc*b
// (folded in epilogue; exact integer counts in fp32). Doubles the same-C-reg
// MFMA reuse distance 4 -> 8 to test the last surviving theory for match's
// 2x-over-floor time: mfma_scale C->C dependency latency (~280cyc) exceeding
// the distance-4 pipe cover (~140cyc). All other theories eliminated
// R6-R14 (TLP, ratio, prefetch, marshalling, phasing).
#define NROW 8192
#define NPAT 1024

typedef unsigned long long u64;
typedef unsigned int u32;
typedef unsigned char u8;
typedef __attribute__((ext_vector_type(4))) int i32x4;
typedef __attribute__((ext_vector_type(8))) int i32x8;
typedef __attribute__((ext_vector_type(16))) float f32x16;

__device__ __forceinline__ u32 bin7(float v, float e0, float e1, float e2,
                                    float e3, float e4, float e5, float e6) {
  return (u32)((v > e0) + (v > e1) + (v > e2) + (v > e3) + (v > e4) +
               (v > e5) + (v > e6));
}

// Quantize 16 consecutive dims -> 16 code bytes, PRE-SHIFTED (bin*4).
__device__ __forceinline__ int4 quant16n(const float4* s4, float e0, float e1,
                                         float e2, float e3, float e4,
                                         float e5, float e6) {
  int4 out;
  int* od = &out.x;
#pragma unroll
  for (int q = 0; q < 4; ++q) {
    float4 a = s4[q];
    od[q] = (int)((bin7(a.x, e0, e1, e2, e3, e4, e5, e6) << 2) |
                  ((bin7(a.y, e0, e1, e2, e3, e4, e5, e6) << 2) << 8) |
                  ((bin7(a.z, e0, e1, e2, e3, e4, e5, e6) << 2) << 16) |
                  ((bin7(a.w, e0, e1, e2, e3, e4, e5, e6) << 2) << 24));
  }
  return out;
}

// ---------------------------------------------------------------------------
// Prep: codes layout [c16 0..31][h 0..1][row][8B]: 8 dims per 8-byte cell,
// so a lane's k-half (h = lane>>5) for one 16-dim iteration is ONE dwordx2.
// ---------------------------------------------------------------------------
__global__ __launch_bounds__(256) void prep_kernel(
    const float* __restrict__ x, const float* __restrict__ patterns,
    const float* __restrict__ edges, u8* __restrict__ xcode2,
    u8* __restrict__ qpc2) {
  const float e0 = edges[0], e1 = edges[1], e2 = edges[2], e3 = edges[3],
              e4 = edges[4], e5 = edges[5], e6 = edges[6];
  const int bid = blockIdx.x, tid = threadIdx.x;

  if (bid < 1024) {
    const int i = bid * 256 + tid;  // 0..262143
    const int row = i & 8191;
    const int c16 = i >> 13;
    const float4* s4 =
        reinterpret_cast<const float4*>(x + ((size_t)row << 9) + (c16 << 4));
    int4 cod = quant16n(s4, e0, e1, e2, e3, e4, e5, e6);
    const u64 lo = (u64)(u32)cod.x | ((u64)(u32)cod.y << 32);  // dims 0..7
    const u64 hi = (u64)(u32)cod.z | ((u64)(u32)cod.w << 32);  // dims 8..15
    *reinterpret_cast<u64*>(
        xcode2 + ((((size_t)c16 * 2 + 0) * 8192 + row) << 3)) = lo;
    *reinterpret_cast<u64*>(
        xcode2 + ((((size_t)c16 * 2 + 1) * 8192 + row) << 3)) = hi;
  } else {
    const int j = (bid - 1024) * 256 + tid;  // 0..32767
    const int pat = j >> 5;
    const int c16 = j & 31;
    const float4* s4 = reinterpret_cast<const float4*>(
        patterns + ((size_t)pat << 9) + (c16 << 4));
    int4 cod = quant16n(s4, e0, e1, e2, e3, e4, e5, e6);
    const u64 lo = (u64)(u32)cod.x | ((u64)(u32)cod.y << 32);
    const u64 hi = (u64)(u32)cod.z | ((u64)(u32)cod.w << 32);
    *reinterpret_cast<u64*>(
        qpc2 + ((((size_t)c16 * 2 + 0) * 1024 + pat) << 3)) = lo;
    *reinterpret_cast<u64*>(
        qpc2 + ((((size_t)c16 * 2 + 1) * 1024 + pat) << 3)) = hi;
  }
}

// Expand 4 dims (pre-shifted codes bin*4 in the 4 bytes of w) into 4 dwords
// of fp4 one-hot nibbles (1.0 = 0x2 at nibble bin). IDENTICAL for A and B.
__device__ __forceinline__ i32x4 expand4(u32 w) {
  i32x4 f;
  f[0] = (int)(2u << (w & 0xFFu));
  f[1] = (int)(2u << ((w >> 8) & 0xFFu));
  f[2] = (int)(2u << ((w >> 16) & 0xFFu));
  f[3] = (int)(2u << (w >> 24));
  return f;
}

__device__ __forceinline__ i32x8 make8(i32x4 v) {
  i32x8 r;
  r[0] = v[0]; r[1] = v[1]; r[2] = v[2]; r[3] = v[3];
  r[4] = 0; r[5] = 0; r[6] = 0; r[7] = 0;  // fp4 uses operand regs 0-3
  return r;
}

#define MFMA_FP4(A, B, C)                                                \
  __builtin_amdgcn_mfma_scale_f32_32x32x64_f8f6f4(                       \
      (A), (B), (C), 4, 4, 0, 0x7F7F7F7F, 0, 0x7F7F7F7F)

// ---------------------------------------------------------------------------
// Match+argmax. Grid 256 x 512 thr (8 waves, 1 block/CU, 2 waves/SIMD).
// Block b: rows b*32..+31, ALL 1024 patterns. Wave w: patterns w*128 + q*32,
// q=0..3. SPLIT accumulators: j=0 -> a-set, j=1 -> b-set (reuse distance 8).
// Epilogue folds a+b, packs keys, LDS+shuffle argmax, wave 0 writes out[].
// ---------------------------------------------------------------------------
__global__ __launch_bounds__(512, 2) void match_kernel(
    const u8* __restrict__ xcode2,  // [32][2][8192][8]
    const u8* __restrict__ qpc2,    // [32][2][1024][8]
    float* __restrict__ out) {
  __shared__ u32 lds_best[8][64];  // 2 KB

  const int tid = threadIdx.x;
  const int lane = tid & 63;
  const int h = lane >> 5;
  const int wid = tid >> 6;  // 0..7
  const int row = blockIdx.x * 32 + (lane & 31);
  const int m0 = wid * 128 + (lane & 31);

  const u8* pR = xcode2 + (((size_t)h * 8192 + row) << 3);
  const u8* pP = qpc2 + (((size_t)h * 1024 + m0) << 3);

  f32x16 acc0a = {0}, acc1a = {0}, acc2a = {0}, acc3a = {0};
  f32x16 acc0b = {0}, acc1b = {0}, acc2b = {0}, acc3b = {0};

  u64 cR = *reinterpret_cast<const u64*>(pR);
  u64 cP0 = *reinterpret_cast<const u64*>(pP);
  u64 cP1 = *reinterpret_cast<const u64*>(pP + 256);
  u64 cP2 = *reinterpret_cast<const u64*>(pP + 512);
  u64 cP3 = *reinterpret_cast<const u64*>(pP + 768);

  for (int c = 0; c < 32; ++c) {
    u64 nR, nP0, nP1, nP2, nP3;
    if (c < 31) {
      const size_t ro = (size_t)(c + 1) << 17;  // 2*8192*8 B per iteration
      const size_t po = (size_t)(c + 1) << 14;  // 2*1024*8 B per iteration
      nR = *reinterpret_cast<const u64*>(pR + ro);
      nP0 = *reinterpret_cast<const u64*>(pP + po);
      nP1 = *reinterpret_cast<const u64*>(pP + po + 256);
      nP2 = *reinterpret_cast<const u64*>(pP + po + 512);
      nP3 = *reinterpret_cast<const u64*>(pP + po + 768);
    }
    {  // j = 0 -> a-set
      const i32x8 b8 = make8(expand4((u32)cR));
      const i32x8 a0 = make8(expand4((u32)cP0));
      const i32x8 a1 = make8(expand4((u32)cP1));
      const i32x8 a2 = make8(expand4((u32)cP2));
      const i32x8 a3 = make8(expand4((u32)cP3));
      acc0a = MFMA_FP4(a0, b8, acc0a);
      acc1a = MFMA_FP4(a1, b8, acc1a);
      acc2a = MFMA_FP4(a2, b8, acc2a);
      acc3a = MFMA_FP4(a3, b8, acc3a);
    }
    {  // j = 1 -> b-set
      const i32x8 b8 = make8(expand4((u32)(cR >> 32)));
      const i32x8 a0 = make8(expand4((u32)(cP0 >> 32)));
      const i32x8 a1 = make8(expand4((u32)(cP1 >> 32)));
      const i32x8 a2 = make8(expand4((u32)(cP2 >> 32)));
      const i32x8 a3 = make8(expand4((u32)(cP3 >> 32)));
      acc0b = MFMA_FP4(a0, b8, acc0b);
      acc1b = MFMA_FP4(a1, b8, acc1b);
      acc2b = MFMA_FP4(a2, b8, acc2b);
      acc3b = MFMA_FP4(a3, b8, acc3b);
    }
    if (c < 31) {
      cR = nR;
      cP0 = nP0;
      cP1 = nP1;
      cP2 = nP2;
      cP3 = nP3;
    }
  }

  // Fold split accs (exact: integer counts), then pack keys.
  // C/D map: col = lane&31 (this lane's row), pl = (r&3) + 8*(r>>2) + 4*h.
  const int hq = h << 2;
  const int wbase = wid * 128;
  u32 best = 0;
#pragma unroll
  for (int r = 0; r < 16; ++r) {
    const int pl = (r & 3) + 8 * (r >> 2) + hq;
    const u32 c0 = (u32)(acc0a[r] + acc0b[r]);
    const u32 c1 = (u32)(acc1a[r] + acc1b[r]);
    const u32 c2 = (u32)(acc2a[r] + acc2b[r]);
    const u32 c3 = (u32)(acc3a[r] + acc3b[r]);
    const u32 k0 = (c0 << 10) | (1023u - (u32)(wbase + pl));
    const u32 k1 = (c1 << 10) | (1023u - (u32)(wbase + 32 + pl));
    const u32 k2 = (c2 << 10) | (1023u - (u32)(wbase + 64 + pl));
    const u32 k3 = (c3 << 10) | (1023u - (u32)(wbase + 96 + pl));
    best = k0 > best ? k0 : best;
    best = k1 > best ? k1 : best;
    best = k2 > best ? k2 : best;
    best = k3 > best ? k3 : best;
  }
  lds_best[wid][lane] = best;
  __syncthreads();

  if (wid == 0) {
    u32 t = lds_best[0][lane];
#pragma unroll
    for (int w = 1; w < 8; ++w) {
      const u32 v = lds_best[w][lane];
      t = v > t ? v : t;
    }
    const u32 o = __shfl_down(t, 32);
    if (lane < 32) {
      const u32 f = o > t ? o : t;
      out[row] = (float)(1023u - (f & 1023u));
      out[NROW + row] = (float)(f >> 10) * (1.0f / 512.0f);
    }
  }
}

extern "C" void kernel_launch(void* const* d_in, const int* in_sizes, int n_in,
                              void* d_out, int out_size, void* d_ws,
                              size_t ws_size, hipStream_t stream) {
  const float* x = (const float*)d_in[0];         // [8192, 512]
  const float* patterns = (const float*)d_in[1];  // [1024, 512]
  const float* edges = (const float*)d_in[2];     // [7]
  float* out = (float*)d_out;                     // 16384 floats

  // Workspace: xcode2 4MB ++ qpc2 512KB.
  u8* xcode2 = (u8*)d_ws;                     // [32][2][8192][8]
  u8* qpc2 = xcode2 + (size_t)64 * NROW * 8;  // [32][2][1024][8]

  prep_kernel<<<1152, 256, 0, stream>>>(x, patterns, edges, xcode2, qpc2);
  match_kernel<<<256, 512, 0, stream>>>(xcode2, qpc2, out);
}